// Round 23
// baseline (172.427 us; speedup 1.0000x reference)
//
#include <hip/hip_runtime.h>
#include <math.h>

#define EPS 1e-6f

typedef _Float16 half2v __attribute__((ext_vector_type(2)));

// bf16 round-to-nearest-even, returned in low 16 bits of a uint.
__device__ __forceinline__ unsigned f2bf(float x) {
    unsigned u = __float_as_uint(x);
    return (u + 0x7FFFu + ((u >> 16) & 1u)) >> 16;
}

// VALU-only butterfly add within 8-lane head groups (no LDS pipe).
__device__ __forceinline__ float dpp_add_xor1(float t) {
    int u = __builtin_amdgcn_update_dpp(0, __float_as_int(t), 0xB1, 0xF, 0xF, true);
    return t + __int_as_float(u);
}
__device__ __forceinline__ float dpp_add_xor2(float t) {
    int u = __builtin_amdgcn_update_dpp(0, __float_as_int(t), 0x4E, 0xF, 0xF, true);
    return t + __int_as_float(u);
}
__device__ __forceinline__ float dpp_add_mirr8(float t) {
    int u = __builtin_amdgcn_update_dpp(0, __float_as_int(t), 0x141, 0xF, 0xF, true);
    return t + __int_as_float(u);
}

__device__ __forceinline__ float fdot2u(unsigned a, unsigned b, float c) {
    return __builtin_amdgcn_fdot2(__builtin_bit_cast(half2v, a),
                                  __builtin_bit_cast(half2v, b), c, false);
}
__device__ __forceinline__ unsigned pk16(float x, float y) {
    return __builtin_bit_cast(unsigned, __builtin_amdgcn_cvt_pkrtz(x, y));
}

// ---------------------------------------------------------------------------
// Fused dispatch (R20 frozen): fp16 LDS tiles + v_dot2_f32_f16 GEMM slices +
// histogram.
//   slice 0: Pt  = A.attn_W[:,0:64]^T                (fp32 out)
//   slice 1: Ph  = A.attn_W[:,64:128]^T + attn_b  -> PQh low 16-bit halves
//   slice 2: Qh  = A.aggr_W[:,0:64]^T   + aggr_b  -> PQh high halves
//   slice 3: Pr  = Ar.attn_W[:,128:192]^T         -> PQr low halves
//   slice 4: Qr  = Ar.aggr_W[:,64:128]^T          -> PQr high halves
// [72]-half pad: row stride 144 B = 4 mod 32 banks (conflict-free; stride
// 0 mod 32 = 38M conflicts, R17). 4x4 acc only (wider blows VGPR to 248+:
// R3/R14/R17/R19). Cooperative grid.sync costs ~100us/sync (R21).
// ---------------------------------------------------------------------------
__global__ __launch_bounds__(256) void tables_hist(
    const float* __restrict__ A, int M,
    const float* __restrict__ Ar, int Mr,
    const float* __restrict__ attn_W,   // [64 x 192]
    const float* __restrict__ aggr_W,   // [64 x 128]
    const float* __restrict__ attn_b, const float* __restrict__ aggr_b,
    float* __restrict__ Pt,
    unsigned short* __restrict__ PQh2,  // ushort view of packed PQh
    unsigned short* __restrict__ PQr2,  // ushort view of packed PQr
    const int* __restrict__ tail, int E, int* __restrict__ deg,
    int gN, int gr)
{
    __shared__ alignas(16) unsigned short As16[64][72];
    __shared__ alignas(16) unsigned short Ws16[64][72];
    const int tid = threadIdx.x;
    const int bid = (int)blockIdx.x;
    const int nEnt = 3 * gN;
    const int nRel = 2 * gr;

    if (bid < nEnt + nRel) {
        int slice, rt, Mrows;
        const float* Asrc;
        if (bid < nEnt) { slice = bid / gN;     rt = bid % gN; Asrc = A;  Mrows = M;  }
        else { int b2 = bid - nEnt; slice = 3 + b2 / gr; rt = b2 % gr; Asrc = Ar; Mrows = Mr; }
        const int r0 = rt * 64;

        // stage A tile (64 rows x 64 k) fp32 -> fp16
        for (int t = tid; t < 1024; t += 256) {
            int r = t >> 4, c4 = (t & 15) << 2;
            float4 v = make_float4(0.f, 0.f, 0.f, 0.f);
            if (r0 + r < Mrows)
                v = *reinterpret_cast<const float4*>(Asrc + (size_t)(r0 + r) * 64 + c4);
            *reinterpret_cast<uint2*>(&As16[r][c4]) =
                make_uint2(pk16(v.x, v.y), pk16(v.z, v.w));
        }
        // stage W slice (out-col c x k) fp32 -> fp16
        const float* Wsrc; int ldw, koff;
        switch (slice) {
        case 0:  Wsrc = attn_W; ldw = 192; koff = 0;   break;
        case 1:  Wsrc = attn_W; ldw = 192; koff = 64;  break;
        case 2:  Wsrc = aggr_W; ldw = 128; koff = 0;   break;
        case 3:  Wsrc = attn_W; ldw = 192; koff = 128; break;
        default: Wsrc = aggr_W; ldw = 128; koff = 64;  break;
        }
        for (int t = tid; t < 1024; t += 256) {
            int c = t >> 4, k4 = (t & 15) << 2;
            float4 v = *reinterpret_cast<const float4*>(
                Wsrc + (size_t)c * ldw + koff + k4);
            *reinterpret_cast<uint2*>(&Ws16[c][k4]) =
                make_uint2(pk16(v.x, v.y), pk16(v.z, v.w));
        }
        __syncthreads();

        const int ti = tid >> 4, tj = tid & 15;
        float acc[4][4];
#pragma unroll
        for (int i = 0; i < 4; ++i)
#pragma unroll
            for (int j = 0; j < 4; ++j) acc[i][j] = 0.f;

#pragma unroll
        for (int k = 0; k < 64; k += 8) {
            uint4 a8[4], w8[4];
#pragma unroll
            for (int i = 0; i < 4; ++i)
                a8[i] = *reinterpret_cast<const uint4*>(&As16[ti + 16 * i][k]);
#pragma unroll
            for (int j = 0; j < 4; ++j)
                w8[j] = *reinterpret_cast<const uint4*>(&Ws16[tj + 16 * j][k]);
#pragma unroll
            for (int i = 0; i < 4; ++i)
#pragma unroll
                for (int j = 0; j < 4; ++j) {
                    float c0 = acc[i][j];
                    c0 = fdot2u(a8[i].x, w8[j].x, c0);
                    c0 = fdot2u(a8[i].y, w8[j].y, c0);
                    c0 = fdot2u(a8[i].z, w8[j].z, c0);
                    c0 = fdot2u(a8[i].w, w8[j].w, c0);
                    acc[i][j] = c0;
                }
        }

        // epilogue per slice
        if (slice == 0) {
#pragma unroll
            for (int i = 0; i < 4; ++i) {
                int r = r0 + ti + 16 * i;
                if (r < M)
#pragma unroll
                    for (int j = 0; j < 4; ++j)
                        Pt[(size_t)r * 64 + tj + 16 * j] = acc[i][j];
            }
        } else if (slice == 1) {
#pragma unroll
            for (int i = 0; i < 4; ++i) {
                int r = r0 + ti + 16 * i;
                if (r < M)
#pragma unroll
                    for (int j = 0; j < 4; ++j) {
                        int c = tj + 16 * j;
                        PQh2[((size_t)r * 64 + c) * 2 + 0] =
                            (unsigned short)f2bf(acc[i][j] + attn_b[c]);
                    }
            }
        } else if (slice == 2) {
#pragma unroll
            for (int i = 0; i < 4; ++i) {
                int r = r0 + ti + 16 * i;
                if (r < M)
#pragma unroll
                    for (int j = 0; j < 4; ++j) {
                        int c = tj + 16 * j;
                        PQh2[((size_t)r * 64 + c) * 2 + 1] =
                            (unsigned short)f2bf(acc[i][j] + aggr_b[c]);
                    }
            }
        } else if (slice == 3) {
#pragma unroll
            for (int i = 0; i < 4; ++i) {
                int r = r0 + ti + 16 * i;
                if (r < Mr)
#pragma unroll
                    for (int j = 0; j < 4; ++j)
                        PQr2[((size_t)r * 64 + tj + 16 * j) * 2 + 0] =
                            (unsigned short)f2bf(acc[i][j]);
            }
        } else {
#pragma unroll
            for (int i = 0; i < 4; ++i) {
                int r = r0 + ti + 16 * i;
                if (r < Mr)
#pragma unroll
                    for (int j = 0; j < 4; ++j)
                        PQr2[((size_t)r * 64 + tj + 16 * j) * 2 + 1] =
                            (unsigned short)f2bf(acc[i][j]);
            }
        }
    } else {
        // -------- histogram (4 edges/thread) --------
        const int base = ((bid - nEnt - nRel) * 256 + tid) * 4;
        if (base + 4 <= E) {
            int4 t4 = *reinterpret_cast<const int4*>(tail + base);
            atomicAdd(&deg[t4.x], 1);
            atomicAdd(&deg[t4.y], 1);
            atomicAdd(&deg[t4.z], 1);
            atomicAdd(&deg[t4.w], 1);
        } else {
            for (int k = 0; k < 4; ++k)
                if (base + k < E) atomicAdd(&deg[tail[base + k]], 1);
        }
    }
}

// ---------------------------------------------------------------------------
// Scan: per-block inclusive scan + block sums; then per-block base reduce.
// ---------------------------------------------------------------------------
__global__ __launch_bounds__(256) void scan_chunk(const int* __restrict__ deg, int n,
                                                  int* __restrict__ incl, int* __restrict__ bsums)
{
    __shared__ int s[256];
    int tid = threadIdx.x;
    int i = blockIdx.x * 256 + tid;
    int v = (i < n) ? deg[i] : 0;
    int acc = v;
    s[tid] = acc;
    __syncthreads();
#pragma unroll
    for (int off = 1; off < 256; off <<= 1) {
        int add = (tid >= off) ? s[tid - off] : 0;
        __syncthreads();
        acc += add;
        s[tid] = acc;
        __syncthreads();
    }
    if (i < n) incl[i] = acc;
    if (tid == 255) bsums[blockIdx.x] = acc;
}

__global__ __launch_bounds__(256) void scan_final2(const int* __restrict__ deg,
                                                   const int* __restrict__ incl,
                                                   const int* __restrict__ bsums, int n,
                                                   int* __restrict__ offs,
                                                   int* __restrict__ cursor)
{
    __shared__ int s[256];
    const int tid = threadIdx.x;
    int partial = 0;
    for (int i = tid; i < (int)blockIdx.x; i += 256) partial += bsums[i];
    s[tid] = partial;
    __syncthreads();
#pragma unroll
    for (int off = 128; off > 0; off >>= 1) {
        if (tid < off) s[tid] += s[tid + off];
        __syncthreads();
    }
    const int base = s[0];
    int i = blockIdx.x * 256 + tid;
    if (i < n) {
        int e = incl[i] - deg[i] + base;
        offs[i] = e;
        cursor[i] = e;
    }
}

// 4 edges/thread placement; shr scatter uses NON-TEMPORAL stores to bypass
// L2 write-allocate (random 4B scatters thrash per-XCD L2 lines: 53.6 MB
// HBM write for a 3.2 MB buffer, R22 counters). NT writes go out as masked
// sector writes with no line-eviction multiplication.
__global__ __launch_bounds__(256) void place_kernel(const int* __restrict__ head,
                                                    const int* __restrict__ tail,
                                                    const int* __restrict__ rel, int E,
                                                    int* __restrict__ cursor,
                                                    unsigned int* __restrict__ shr)
{
    const int base = (blockIdx.x * 256 + threadIdx.x) * 4;
    if (base + 4 <= E) {
        int4 h = *reinterpret_cast<const int4*>(head + base);
        int4 t = *reinterpret_cast<const int4*>(tail + base);
        int4 r = *reinterpret_cast<const int4*>(rel + base);
        int p;
        p = atomicAdd(&cursor[t.x], 1);
        __builtin_nontemporal_store(((unsigned)h.x << 8) | (unsigned)r.x, shr + p);
        p = atomicAdd(&cursor[t.y], 1);
        __builtin_nontemporal_store(((unsigned)h.y << 8) | (unsigned)r.y, shr + p);
        p = atomicAdd(&cursor[t.z], 1);
        __builtin_nontemporal_store(((unsigned)h.z << 8) | (unsigned)r.z, shr + p);
        p = atomicAdd(&cursor[t.w], 1);
        __builtin_nontemporal_store(((unsigned)h.w << 8) | (unsigned)r.w, shr + p);
    } else {
        for (int k = 0; k < 4; ++k) {
            int e = base + k;
            if (e < E) {
                int p = atomicAdd(&cursor[tail[e]], 1);
                __builtin_nontemporal_store(
                    ((unsigned)head[e] << 8) | (unsigned)rel[e], shr + p);
            }
        }
    }
}

// ---------------------------------------------------------------------------
// Main: one wave per node, lane = output dim. Predicated 8-edge pipeline with
// ping-pong prefetch; tail edges clamp to a valid address and contribute 0
// via a 0/1 mask. PQh/PQr bf16-packed, 256 B row stride. DPP head reduce.
// No-max softmax. (Frozen from R11.)
// ---------------------------------------------------------------------------
__global__ __launch_bounds__(256) void ingram_main(
    const float* __restrict__ Pt,
    const unsigned* __restrict__ PQh,    // {bf16 Ph+attn_b | bf16 Qh+aggr_b}
    const unsigned* __restrict__ PQr,    // {bf16 Pr | bf16 Qr}
    const int* __restrict__ deg, const int* __restrict__ off,
    const unsigned* __restrict__ shr,
    const float* __restrict__ attn_vec,
    float* __restrict__ out, int N)
{
    const int lane = threadIdx.x & 63;
    const int node = blockIdx.x * 4 + (threadIdx.x >> 6);
    if (node >= N) return;

    const float vec = attn_vec[lane];
    const float ptd = Pt[(size_t)node * 64 + lane];
    const char* HBc = (const char*)PQh;
    const char* RBc = (const char*)PQr;
    const unsigned loff4 = (unsigned)lane << 2;

    const int start = __builtin_amdgcn_readfirstlane(off[node]);
    const int dg    = __builtin_amdgcn_readfirstlane(deg[node]);

    float S = 0.f, O = 0.f, SP = 0.f, SQ = 0.f;

    const int ng = (dg + 7) >> 3;        // groups of 8 edges
    unsigned Ah[8], Ar8[8], Bh[8], Br8[8];

#define LOADG(gbase, H, R)                                                   \
    {                                                                        \
        _Pragma("unroll")                                                    \
        for (int k = 0; k < 8; ++k) {                                        \
            int idx = (gbase) + k;                                           \
            int e   = start + ((idx < dg) ? idx : (dg - 1));                 \
            unsigned p = shr[e];  /* uniform addr -> scalar load */          \
            H[k] = *(const unsigned*)(HBc + (p & 0xFFFFFF00u) + loff4);      \
            R[k] = *(const unsigned*)(RBc + ((p & 255u) << 8) + loff4);      \
        }                                                                    \
    }

#define COMPUTE(gbase, H, R)                                                 \
    {                                                                        \
        _Pragma("unroll")                                                    \
        for (int k = 0; k < 8; ++k) {                                        \
            const int idx = (gbase) + k;                                     \
            const float valid = (idx < dg) ? 1.f : 0.f;                      \
            unsigned hb = H[k], rb = R[k];                                   \
            float hx = __uint_as_float(hb << 16);                            \
            float hy = __uint_as_float(hb & 0xFFFF0000u);                    \
            float rx = __uint_as_float(rb << 16);                            \
            float ry = __uint_as_float(rb & 0xFFFF0000u);                    \
            SP = fmaf(rx, valid, SP);                                        \
            SQ = fmaf(ry, valid, SQ);                                        \
            float pre = ptd + hx + rx;                                       \
            float a   = fmaxf(pre, 0.2f * pre);                              \
            float t   = a * vec;                                             \
            t = dpp_add_xor1(t);                                             \
            t = dpp_add_xor2(t);                                             \
            t = dpp_add_mirr8(t);                                            \
            float av = __expf(t) * valid;                                    \
            S += av;                                                         \
            O = fmaf(av, hy + ry, O);                                        \
        }                                                                    \
    }

    if (ng > 0) LOADG(0, Ah, Ar8);
    for (int g = 0; g < ng; g += 2) {
        if (g + 1 < ng) LOADG((g + 1) * 8, Bh, Br8);
        COMPUTE(g * 8, Ah, Ar8);
        if (g + 1 < ng) {
            if (g + 2 < ng) LOADG((g + 2) * 8, Ah, Ar8);
            COMPUTE((g + 1) * 8, Bh, Br8);
        }
    }
#undef LOADG
#undef COMPUTE

    // self-loop: rel features = (sum of incoming Pr/Qr)/(deg+eps)
    {
        const float inv = 1.f / ((float)dg + EPS);
        unsigned hb = *(const unsigned*)(HBc + ((unsigned)node << 8) + loff4);
        float hx = __uint_as_float(hb << 16);
        float hy = __uint_as_float(hb & 0xFFFF0000u);
        float pre = ptd + hx + SP * inv;
        float a   = fmaxf(pre, 0.2f * pre);
        float t   = a * vec;
        t = dpp_add_xor1(t);
        t = dpp_add_xor2(t);
        t = dpp_add_mirr8(t);
        float av = __expf(t);
        S += av;
        O = fmaf(av, hy + SQ * inv, O);
    }

    out[(size_t)node * 64 + lane] = O / (S + EPS);
}

// ---------------------------------------------------------------------------
extern "C" void kernel_launch(void* const* d_in, const int* in_sizes, int n_in,
                              void* d_out, int out_size, void* d_ws, size_t ws_size,
                              hipStream_t stream)
{
    const float* emb_ent  = (const float*)d_in[0];
    const float* emb_rel  = (const float*)d_in[1];
    const float* attn_W   = (const float*)d_in[2];   // [64 x 192]
    const float* attn_b   = (const float*)d_in[3];
    const float* attn_vec = (const float*)d_in[4];   // 64
    const float* aggr_W   = (const float*)d_in[5];   // [64 x 128]
    const float* aggr_b   = (const float*)d_in[6];
    const int*   head     = (const int*)d_in[7];
    const int*   tail     = (const int*)d_in[8];
    const int*   rel      = (const int*)d_in[9];

    const int N = in_sizes[0] / 64;
    const int R = in_sizes[1] / 64;
    const int E = in_sizes[7];

    char* w = (char*)d_ws;
    float*    Pt  = (float*)w;        w += (size_t)N * 64 * sizeof(float);
    unsigned* PQh = (unsigned*)w;     w += (size_t)N * 64 * sizeof(unsigned);
    unsigned* PQr = (unsigned*)w;     w += (size_t)R * 64 * sizeof(unsigned);
    int* deg    = (int*)w;            w += (size_t)N * sizeof(int);
    int* incl   = (int*)w;            w += (size_t)N * sizeof(int);
    int* offs   = (int*)w;            w += (size_t)N * sizeof(int);
    int* cursor = (int*)w;            w += (size_t)N * sizeof(int);
    int* bsums  = (int*)w;            w += 256 * sizeof(int);
    unsigned int* shr = (unsigned int*)w;  w += (size_t)E * sizeof(unsigned int);

    hipMemsetAsync(deg, 0, (size_t)N * sizeof(int), stream);

    // fused: 5 GEMM slice ranges + degree histogram
    int gN = (N + 63) / 64;
    int gr = (R + 63) / 64;
    int gH = (E + 1023) / 1024;
    tables_hist<<<3 * gN + 2 * gr + gH, 256, 0, stream>>>(
        emb_ent, N, emb_rel, R, attn_W, aggr_W, attn_b, aggr_b,
        Pt, (unsigned short*)PQh, (unsigned short*)PQr,
        tail, E, deg, gN, gr);

    int nb = (N + 255) / 256;
    scan_chunk<<<nb, 256, 0, stream>>>(deg, N, incl, bsums);
    scan_final2<<<nb, 256, 0, stream>>>(deg, incl, bsums, N, offs, cursor);
    place_kernel<<<(E + 1023) / 1024, 256, 0, stream>>>(head, tail, rel, E, cursor, shr);

    // per-node aggregation
    ingram_main<<<(N + 3) / 4, 256, 0, stream>>>(Pt, PQh, PQr, deg, offs, shr,
                                                 attn_vec, (float*)d_out, N);
}

// Round 24
// 134.624 us; speedup vs baseline: 1.2808x; 1.2808x over previous
//
#include <hip/hip_runtime.h>
#include <math.h>

#define EPS 1e-6f

typedef _Float16 half2v __attribute__((ext_vector_type(2)));

// bf16 round-to-nearest-even, returned in low 16 bits of a uint.
__device__ __forceinline__ unsigned f2bf(float x) {
    unsigned u = __float_as_uint(x);
    return (u + 0x7FFFu + ((u >> 16) & 1u)) >> 16;
}

// VALU-only butterfly add within 8-lane head groups (no LDS pipe).
__device__ __forceinline__ float dpp_add_xor1(float t) {
    int u = __builtin_amdgcn_update_dpp(0, __float_as_int(t), 0xB1, 0xF, 0xF, true);
    return t + __int_as_float(u);
}
__device__ __forceinline__ float dpp_add_xor2(float t) {
    int u = __builtin_amdgcn_update_dpp(0, __float_as_int(t), 0x4E, 0xF, 0xF, true);
    return t + __int_as_float(u);
}
__device__ __forceinline__ float dpp_add_mirr8(float t) {
    int u = __builtin_amdgcn_update_dpp(0, __float_as_int(t), 0x141, 0xF, 0xF, true);
    return t + __int_as_float(u);
}

__device__ __forceinline__ float fdot2u(unsigned a, unsigned b, float c) {
    return __builtin_amdgcn_fdot2(__builtin_bit_cast(half2v, a),
                                  __builtin_bit_cast(half2v, b), c, false);
}
__device__ __forceinline__ unsigned pk16(float x, float y) {
    return __builtin_bit_cast(unsigned, __builtin_amdgcn_cvt_pkrtz(x, y));
}

// ---------------------------------------------------------------------------
// Fused dispatch: fp16 LDS GEMM slices + histogram-with-rank.
//   slice 0: Pt  = A.attn_W[:,0:64]^T                (fp32 out)
//   slice 1: Ph  = A.attn_W[:,64:128]^T + attn_b  -> PQh low 16-bit halves
//   slice 2: Qh  = A.aggr_W[:,0:64]^T   + aggr_b  -> PQh high halves
//   slice 3: Pr  = Ar.attn_W[:,128:192]^T         -> PQr low halves
//   slice 4: Qr  = Ar.aggr_W[:,64:128]^T          -> PQr high halves
// hist branch now captures atomicAdd's return as the edge's within-node rank
// (stored coalesced) -> place_kernel needs NO atomics.
// [72]-half pad: stride 144 B = 4 mod 32 banks (conflict-free; 0 mod 32 was
// 38M conflicts, R17). 4x4 acc only (wider blows VGPR: R3/R14/R17/R19).
// Coop grid.sync ~100us/sync (R21). NT stores worsen scatter (R23).
// ---------------------------------------------------------------------------
__global__ __launch_bounds__(256) void tables_hist(
    const float* __restrict__ A, int M,
    const float* __restrict__ Ar, int Mr,
    const float* __restrict__ attn_W,   // [64 x 192]
    const float* __restrict__ aggr_W,   // [64 x 128]
    const float* __restrict__ attn_b, const float* __restrict__ aggr_b,
    float* __restrict__ Pt,
    unsigned short* __restrict__ PQh2,  // ushort view of packed PQh
    unsigned short* __restrict__ PQr2,  // ushort view of packed PQr
    const int* __restrict__ tail, int E, int* __restrict__ deg,
    int* __restrict__ rank,
    int gN, int gr)
{
    __shared__ alignas(16) unsigned short As16[64][72];
    __shared__ alignas(16) unsigned short Ws16[64][72];
    const int tid = threadIdx.x;
    const int bid = (int)blockIdx.x;
    const int nEnt = 3 * gN;
    const int nRel = 2 * gr;

    if (bid < nEnt + nRel) {
        int slice, rt, Mrows;
        const float* Asrc;
        if (bid < nEnt) { slice = bid / gN;     rt = bid % gN; Asrc = A;  Mrows = M;  }
        else { int b2 = bid - nEnt; slice = 3 + b2 / gr; rt = b2 % gr; Asrc = Ar; Mrows = Mr; }
        const int r0 = rt * 64;

        // stage A tile (64 rows x 64 k) fp32 -> fp16
        for (int t = tid; t < 1024; t += 256) {
            int r = t >> 4, c4 = (t & 15) << 2;
            float4 v = make_float4(0.f, 0.f, 0.f, 0.f);
            if (r0 + r < Mrows)
                v = *reinterpret_cast<const float4*>(Asrc + (size_t)(r0 + r) * 64 + c4);
            *reinterpret_cast<uint2*>(&As16[r][c4]) =
                make_uint2(pk16(v.x, v.y), pk16(v.z, v.w));
        }
        // stage W slice (out-col c x k) fp32 -> fp16
        const float* Wsrc; int ldw, koff;
        switch (slice) {
        case 0:  Wsrc = attn_W; ldw = 192; koff = 0;   break;
        case 1:  Wsrc = attn_W; ldw = 192; koff = 64;  break;
        case 2:  Wsrc = aggr_W; ldw = 128; koff = 0;   break;
        case 3:  Wsrc = attn_W; ldw = 192; koff = 128; break;
        default: Wsrc = aggr_W; ldw = 128; koff = 64;  break;
        }
        for (int t = tid; t < 1024; t += 256) {
            int c = t >> 4, k4 = (t & 15) << 2;
            float4 v = *reinterpret_cast<const float4*>(
                Wsrc + (size_t)c * ldw + koff + k4);
            *reinterpret_cast<uint2*>(&Ws16[c][k4]) =
                make_uint2(pk16(v.x, v.y), pk16(v.z, v.w));
        }
        __syncthreads();

        const int ti = tid >> 4, tj = tid & 15;
        float acc[4][4];
#pragma unroll
        for (int i = 0; i < 4; ++i)
#pragma unroll
            for (int j = 0; j < 4; ++j) acc[i][j] = 0.f;

#pragma unroll
        for (int k = 0; k < 64; k += 8) {
            uint4 a8[4], w8[4];
#pragma unroll
            for (int i = 0; i < 4; ++i)
                a8[i] = *reinterpret_cast<const uint4*>(&As16[ti + 16 * i][k]);
#pragma unroll
            for (int j = 0; j < 4; ++j)
                w8[j] = *reinterpret_cast<const uint4*>(&Ws16[tj + 16 * j][k]);
#pragma unroll
            for (int i = 0; i < 4; ++i)
#pragma unroll
                for (int j = 0; j < 4; ++j) {
                    float c0 = acc[i][j];
                    c0 = fdot2u(a8[i].x, w8[j].x, c0);
                    c0 = fdot2u(a8[i].y, w8[j].y, c0);
                    c0 = fdot2u(a8[i].z, w8[j].z, c0);
                    c0 = fdot2u(a8[i].w, w8[j].w, c0);
                    acc[i][j] = c0;
                }
        }

        // epilogue per slice
        if (slice == 0) {
#pragma unroll
            for (int i = 0; i < 4; ++i) {
                int r = r0 + ti + 16 * i;
                if (r < M)
#pragma unroll
                    for (int j = 0; j < 4; ++j)
                        Pt[(size_t)r * 64 + tj + 16 * j] = acc[i][j];
            }
        } else if (slice == 1) {
#pragma unroll
            for (int i = 0; i < 4; ++i) {
                int r = r0 + ti + 16 * i;
                if (r < M)
#pragma unroll
                    for (int j = 0; j < 4; ++j) {
                        int c = tj + 16 * j;
                        PQh2[((size_t)r * 64 + c) * 2 + 0] =
                            (unsigned short)f2bf(acc[i][j] + attn_b[c]);
                    }
            }
        } else if (slice == 2) {
#pragma unroll
            for (int i = 0; i < 4; ++i) {
                int r = r0 + ti + 16 * i;
                if (r < M)
#pragma unroll
                    for (int j = 0; j < 4; ++j) {
                        int c = tj + 16 * j;
                        PQh2[((size_t)r * 64 + c) * 2 + 1] =
                            (unsigned short)f2bf(acc[i][j] + aggr_b[c]);
                    }
            }
        } else if (slice == 3) {
#pragma unroll
            for (int i = 0; i < 4; ++i) {
                int r = r0 + ti + 16 * i;
                if (r < Mr)
#pragma unroll
                    for (int j = 0; j < 4; ++j)
                        PQr2[((size_t)r * 64 + tj + 16 * j) * 2 + 0] =
                            (unsigned short)f2bf(acc[i][j]);
            }
        } else {
#pragma unroll
            for (int i = 0; i < 4; ++i) {
                int r = r0 + ti + 16 * i;
                if (r < Mr)
#pragma unroll
                    for (int j = 0; j < 4; ++j)
                        PQr2[((size_t)r * 64 + tj + 16 * j) * 2 + 1] =
                            (unsigned short)f2bf(acc[i][j]);
            }
        }
    } else {
        // -------- histogram + rank capture (4 edges/thread) --------
        const int base = ((bid - nEnt - nRel) * 256 + tid) * 4;
        if (base + 4 <= E) {
            int4 t4 = *reinterpret_cast<const int4*>(tail + base);
            int4 rk;
            rk.x = atomicAdd(&deg[t4.x], 1);
            rk.y = atomicAdd(&deg[t4.y], 1);
            rk.z = atomicAdd(&deg[t4.z], 1);
            rk.w = atomicAdd(&deg[t4.w], 1);
            *reinterpret_cast<int4*>(rank + base) = rk;   // coalesced
        } else {
            for (int k = 0; k < 4; ++k)
                if (base + k < E) rank[base + k] = atomicAdd(&deg[tail[base + k]], 1);
        }
    }
}

// ---------------------------------------------------------------------------
// Scan: per-block inclusive scan + block sums; then per-block base reduce.
// ---------------------------------------------------------------------------
__global__ __launch_bounds__(256) void scan_chunk(const int* __restrict__ deg, int n,
                                                  int* __restrict__ incl, int* __restrict__ bsums)
{
    __shared__ int s[256];
    int tid = threadIdx.x;
    int i = blockIdx.x * 256 + tid;
    int v = (i < n) ? deg[i] : 0;
    int acc = v;
    s[tid] = acc;
    __syncthreads();
#pragma unroll
    for (int off = 1; off < 256; off <<= 1) {
        int add = (tid >= off) ? s[tid - off] : 0;
        __syncthreads();
        acc += add;
        s[tid] = acc;
        __syncthreads();
    }
    if (i < n) incl[i] = acc;
    if (tid == 255) bsums[blockIdx.x] = acc;
}

__global__ __launch_bounds__(256) void scan_final2(const int* __restrict__ deg,
                                                   const int* __restrict__ incl,
                                                   const int* __restrict__ bsums, int n,
                                                   int* __restrict__ offs)
{
    __shared__ int s[256];
    const int tid = threadIdx.x;
    int partial = 0;
    for (int i = tid; i < (int)blockIdx.x; i += 256) partial += bsums[i];
    s[tid] = partial;
    __syncthreads();
#pragma unroll
    for (int off = 128; off > 0; off >>= 1) {
        if (tid < off) s[tid] += s[tid + off];
        __syncthreads();
    }
    const int base = s[0];
    int i = blockIdx.x * 256 + tid;
    if (i < n)
        offs[i] = incl[i] - deg[i] + base;
}

// Atomic-free placement: p = offs[tail] + rank (rank captured in histogram).
// Coalesced int4 reads of head/tail/rel/rank; offs gather is a 200 KB
// L2-resident table; only the shr scatter store remains random.
__global__ __launch_bounds__(256) void place_kernel(const int* __restrict__ head,
                                                    const int* __restrict__ tail,
                                                    const int* __restrict__ rel, int E,
                                                    const int* __restrict__ offs,
                                                    const int* __restrict__ rank,
                                                    unsigned int* __restrict__ shr)
{
    const int base = (blockIdx.x * 256 + threadIdx.x) * 4;
    if (base + 4 <= E) {
        int4 h  = *reinterpret_cast<const int4*>(head + base);
        int4 t  = *reinterpret_cast<const int4*>(tail + base);
        int4 r  = *reinterpret_cast<const int4*>(rel + base);
        int4 rk = *reinterpret_cast<const int4*>(rank + base);
        shr[offs[t.x] + rk.x] = ((unsigned)h.x << 8) | (unsigned)r.x;
        shr[offs[t.y] + rk.y] = ((unsigned)h.y << 8) | (unsigned)r.y;
        shr[offs[t.z] + rk.z] = ((unsigned)h.z << 8) | (unsigned)r.z;
        shr[offs[t.w] + rk.w] = ((unsigned)h.w << 8) | (unsigned)r.w;
    } else {
        for (int k = 0; k < 4; ++k) {
            int e = base + k;
            if (e < E)
                shr[offs[tail[e]] + rank[e]] =
                    ((unsigned)head[e] << 8) | (unsigned)rel[e];
        }
    }
}

// ---------------------------------------------------------------------------
// Main: one wave per node, lane = output dim. Predicated 8-edge pipeline with
// ping-pong prefetch; tail edges clamp to a valid address and contribute 0
// via a 0/1 mask. PQh/PQr bf16-packed, 256 B row stride. DPP head reduce.
// No-max softmax. (Frozen from R11.)
// ---------------------------------------------------------------------------
__global__ __launch_bounds__(256) void ingram_main(
    const float* __restrict__ Pt,
    const unsigned* __restrict__ PQh,    // {bf16 Ph+attn_b | bf16 Qh+aggr_b}
    const unsigned* __restrict__ PQr,    // {bf16 Pr | bf16 Qr}
    const int* __restrict__ deg, const int* __restrict__ off,
    const unsigned* __restrict__ shr,
    const float* __restrict__ attn_vec,
    float* __restrict__ out, int N)
{
    const int lane = threadIdx.x & 63;
    const int node = blockIdx.x * 4 + (threadIdx.x >> 6);
    if (node >= N) return;

    const float vec = attn_vec[lane];
    const float ptd = Pt[(size_t)node * 64 + lane];
    const char* HBc = (const char*)PQh;
    const char* RBc = (const char*)PQr;
    const unsigned loff4 = (unsigned)lane << 2;

    const int start = __builtin_amdgcn_readfirstlane(off[node]);
    const int dg    = __builtin_amdgcn_readfirstlane(deg[node]);

    float S = 0.f, O = 0.f, SP = 0.f, SQ = 0.f;

    const int ng = (dg + 7) >> 3;        // groups of 8 edges
    unsigned Ah[8], Ar8[8], Bh[8], Br8[8];

#define LOADG(gbase, H, R)                                                   \
    {                                                                        \
        _Pragma("unroll")                                                    \
        for (int k = 0; k < 8; ++k) {                                        \
            int idx = (gbase) + k;                                           \
            int e   = start + ((idx < dg) ? idx : (dg - 1));                 \
            unsigned p = shr[e];  /* uniform addr -> scalar load */          \
            H[k] = *(const unsigned*)(HBc + (p & 0xFFFFFF00u) + loff4);      \
            R[k] = *(const unsigned*)(RBc + ((p & 255u) << 8) + loff4);      \
        }                                                                    \
    }

#define COMPUTE(gbase, H, R)                                                 \
    {                                                                        \
        _Pragma("unroll")                                                    \
        for (int k = 0; k < 8; ++k) {                                        \
            const int idx = (gbase) + k;                                     \
            const float valid = (idx < dg) ? 1.f : 0.f;                      \
            unsigned hb = H[k], rb = R[k];                                   \
            float hx = __uint_as_float(hb << 16);                            \
            float hy = __uint_as_float(hb & 0xFFFF0000u);                    \
            float rx = __uint_as_float(rb << 16);                            \
            float ry = __uint_as_float(rb & 0xFFFF0000u);                    \
            SP = fmaf(rx, valid, SP);                                        \
            SQ = fmaf(ry, valid, SQ);                                        \
            float pre = ptd + hx + rx;                                       \
            float a   = fmaxf(pre, 0.2f * pre);                              \
            float t   = a * vec;                                             \
            t = dpp_add_xor1(t);                                             \
            t = dpp_add_xor2(t);                                             \
            t = dpp_add_mirr8(t);                                            \
            float av = __expf(t) * valid;                                    \
            S += av;                                                         \
            O = fmaf(av, hy + ry, O);                                        \
        }                                                                    \
    }

    if (ng > 0) LOADG(0, Ah, Ar8);
    for (int g = 0; g < ng; g += 2) {
        if (g + 1 < ng) LOADG((g + 1) * 8, Bh, Br8);
        COMPUTE(g * 8, Ah, Ar8);
        if (g + 1 < ng) {
            if (g + 2 < ng) LOADG((g + 2) * 8, Ah, Ar8);
            COMPUTE((g + 1) * 8, Bh, Br8);
        }
    }
#undef LOADG
#undef COMPUTE

    // self-loop: rel features = (sum of incoming Pr/Qr)/(deg+eps)
    {
        const float inv = 1.f / ((float)dg + EPS);
        unsigned hb = *(const unsigned*)(HBc + ((unsigned)node << 8) + loff4);
        float hx = __uint_as_float(hb << 16);
        float hy = __uint_as_float(hb & 0xFFFF0000u);
        float pre = ptd + hx + SP * inv;
        float a   = fmaxf(pre, 0.2f * pre);
        float t   = a * vec;
        t = dpp_add_xor1(t);
        t = dpp_add_xor2(t);
        t = dpp_add_mirr8(t);
        float av = __expf(t);
        S += av;
        O = fmaf(av, hy + SQ * inv, O);
    }

    out[(size_t)node * 64 + lane] = O / (S + EPS);
}

// ---------------------------------------------------------------------------
extern "C" void kernel_launch(void* const* d_in, const int* in_sizes, int n_in,
                              void* d_out, int out_size, void* d_ws, size_t ws_size,
                              hipStream_t stream)
{
    const float* emb_ent  = (const float*)d_in[0];
    const float* emb_rel  = (const float*)d_in[1];
    const float* attn_W   = (const float*)d_in[2];   // [64 x 192]
    const float* attn_b   = (const float*)d_in[3];
    const float* attn_vec = (const float*)d_in[4];   // 64
    const float* aggr_W   = (const float*)d_in[5];   // [64 x 128]
    const float* aggr_b   = (const float*)d_in[6];
    const int*   head     = (const int*)d_in[7];
    const int*   tail     = (const int*)d_in[8];
    const int*   rel      = (const int*)d_in[9];

    const int N = in_sizes[0] / 64;
    const int R = in_sizes[1] / 64;
    const int E = in_sizes[7];

    char* w = (char*)d_ws;
    float*    Pt  = (float*)w;        w += (size_t)N * 64 * sizeof(float);
    unsigned* PQh = (unsigned*)w;     w += (size_t)N * 64 * sizeof(unsigned);
    unsigned* PQr = (unsigned*)w;     w += (size_t)R * 64 * sizeof(unsigned);
    int* deg    = (int*)w;            w += (size_t)N * sizeof(int);
    int* incl   = (int*)w;            w += (size_t)N * sizeof(int);
    int* offs   = (int*)w;            w += (size_t)N * sizeof(int);
    int* bsums  = (int*)w;            w += 256 * sizeof(int);
    int* rank   = (int*)w;            w += (size_t)E * sizeof(int);
    unsigned int* shr = (unsigned int*)w;  w += (size_t)E * sizeof(unsigned int);

    hipMemsetAsync(deg, 0, (size_t)N * sizeof(int), stream);

    // fused: 5 GEMM slice ranges + histogram (rank-capturing)
    int gN = (N + 63) / 64;
    int gr = (R + 63) / 64;
    int gH = (E + 1023) / 1024;
    tables_hist<<<3 * gN + 2 * gr + gH, 256, 0, stream>>>(
        emb_ent, N, emb_rel, R, attn_W, aggr_W, attn_b, aggr_b,
        Pt, (unsigned short*)PQh, (unsigned short*)PQr,
        tail, E, deg, rank, gN, gr);

    int nb = (N + 255) / 256;
    scan_chunk<<<nb, 256, 0, stream>>>(deg, N, incl, bsums);
    scan_final2<<<nb, 256, 0, stream>>>(deg, incl, bsums, N, offs);
    place_kernel<<<(E + 1023) / 1024, 256, 0, stream>>>(head, tail, rel, E,
                                                        offs, rank, shr);

    // per-node aggregation
    ingram_main<<<(N + 3) / 4, 256, 0, stream>>>(Pt, PQh, PQr, deg, offs, shr,
                                                 attn_vec, (float*)d_out, N);
}

// Round 25
// 128.149 us; speedup vs baseline: 1.3455x; 1.0505x over previous
//
#include <hip/hip_runtime.h>
#include <math.h>

#define EPS 1e-6f

typedef _Float16 half2v __attribute__((ext_vector_type(2)));

// bf16 round-to-nearest-even, returned in low 16 bits of a uint.
__device__ __forceinline__ unsigned f2bf(float x) {
    unsigned u = __float_as_uint(x);
    return (u + 0x7FFFu + ((u >> 16) & 1u)) >> 16;
}

// VALU-only butterfly add within 8-lane head groups (no LDS pipe).
__device__ __forceinline__ float dpp_add_xor1(float t) {
    int u = __builtin_amdgcn_update_dpp(0, __float_as_int(t), 0xB1, 0xF, 0xF, true);
    return t + __int_as_float(u);
}
__device__ __forceinline__ float dpp_add_xor2(float t) {
    int u = __builtin_amdgcn_update_dpp(0, __float_as_int(t), 0x4E, 0xF, 0xF, true);
    return t + __int_as_float(u);
}
__device__ __forceinline__ float dpp_add_mirr8(float t) {
    int u = __builtin_amdgcn_update_dpp(0, __float_as_int(t), 0x141, 0xF, 0xF, true);
    return t + __int_as_float(u);
}

__device__ __forceinline__ float fdot2u(unsigned a, unsigned b, float c) {
    return __builtin_amdgcn_fdot2(__builtin_bit_cast(half2v, a),
                                  __builtin_bit_cast(half2v, b), c, false);
}
__device__ __forceinline__ unsigned pk16(float x, float y) {
    return __builtin_bit_cast(unsigned, __builtin_amdgcn_cvt_pkrtz(x, y));
}

// ---------------------------------------------------------------------------
// Fused dispatch: HISTOGRAM FIRST (bid < gH; latency-bound returning atomics
// start immediately and hide under the GEMM blocks), then fp16 GEMM slices.
//   slice 0: Pt  = A.attn_W[:,0:64]^T                (fp32 out)
//   slice 1: Ph  = A.attn_W[:,64:128]^T + attn_b  -> PQh low 16-bit halves
//   slice 2: Qh  = A.aggr_W[:,0:64]^T   + aggr_b  -> PQh high halves
//   slice 3: Pr  = Ar.attn_W[:,128:192]^T         -> PQr low halves
//   slice 4: Qr  = Ar.aggr_W[:,64:128]^T          -> PQr high halves
// hist captures atomicAdd's return as the edge's within-node rank (stored
// coalesced) -> place_kernel needs NO atomics (R24: -22us).
// [72]-half pad: stride 144 B = 4 mod 32 banks (conflict-free; 0 mod 32 was
// 38M conflicts, R17). 4x4 acc only (wider blows VGPR: R3/R14/R17/R19).
// Coop grid.sync ~100us/sync (R21). NT stores worsen scatter (R23).
// ---------------------------------------------------------------------------
__global__ __launch_bounds__(256) void tables_hist(
    const float* __restrict__ A, int M,
    const float* __restrict__ Ar, int Mr,
    const float* __restrict__ attn_W,   // [64 x 192]
    const float* __restrict__ aggr_W,   // [64 x 128]
    const float* __restrict__ attn_b, const float* __restrict__ aggr_b,
    float* __restrict__ Pt,
    unsigned short* __restrict__ PQh2,  // ushort view of packed PQh
    unsigned short* __restrict__ PQr2,  // ushort view of packed PQr
    const int* __restrict__ tail, int E, int* __restrict__ deg,
    int* __restrict__ rank,
    int gN, int gr, int gH)
{
    __shared__ alignas(16) unsigned short As16[64][72];
    __shared__ alignas(16) unsigned short Ws16[64][72];
    const int tid = threadIdx.x;
    const int bid = (int)blockIdx.x;

    if (bid < gH) {
        // -------- histogram + rank capture (4 edges/thread), FIRST --------
        const int base = (bid * 256 + tid) * 4;
        if (base + 4 <= E) {
            int4 t4 = *reinterpret_cast<const int4*>(tail + base);
            int4 rk;
            rk.x = atomicAdd(&deg[t4.x], 1);
            rk.y = atomicAdd(&deg[t4.y], 1);
            rk.z = atomicAdd(&deg[t4.z], 1);
            rk.w = atomicAdd(&deg[t4.w], 1);
            *reinterpret_cast<int4*>(rank + base) = rk;   // coalesced
        } else {
            for (int k = 0; k < 4; ++k)
                if (base + k < E) rank[base + k] = atomicAdd(&deg[tail[base + k]], 1);
        }
        return;
    }

    const int b1 = bid - gH;
    const int nEnt = 3 * gN;
    int slice, rt, Mrows;
    const float* Asrc;
    if (b1 < nEnt) { slice = b1 / gN;     rt = b1 % gN; Asrc = A;  Mrows = M;  }
    else { int b2 = b1 - nEnt; slice = 3 + b2 / gr; rt = b2 % gr; Asrc = Ar; Mrows = Mr; }
    const int r0 = rt * 64;

    // stage A tile (64 rows x 64 k) fp32 -> fp16
    for (int t = tid; t < 1024; t += 256) {
        int r = t >> 4, c4 = (t & 15) << 2;
        float4 v = make_float4(0.f, 0.f, 0.f, 0.f);
        if (r0 + r < Mrows)
            v = *reinterpret_cast<const float4*>(Asrc + (size_t)(r0 + r) * 64 + c4);
        *reinterpret_cast<uint2*>(&As16[r][c4]) =
            make_uint2(pk16(v.x, v.y), pk16(v.z, v.w));
    }
    // stage W slice (out-col c x k) fp32 -> fp16
    const float* Wsrc; int ldw, koff;
    switch (slice) {
    case 0:  Wsrc = attn_W; ldw = 192; koff = 0;   break;
    case 1:  Wsrc = attn_W; ldw = 192; koff = 64;  break;
    case 2:  Wsrc = aggr_W; ldw = 128; koff = 0;   break;
    case 3:  Wsrc = attn_W; ldw = 192; koff = 128; break;
    default: Wsrc = aggr_W; ldw = 128; koff = 64;  break;
    }
    for (int t = tid; t < 1024; t += 256) {
        int c = t >> 4, k4 = (t & 15) << 2;
        float4 v = *reinterpret_cast<const float4*>(
            Wsrc + (size_t)c * ldw + koff + k4);
        *reinterpret_cast<uint2*>(&Ws16[c][k4]) =
            make_uint2(pk16(v.x, v.y), pk16(v.z, v.w));
    }
    __syncthreads();

    const int ti = tid >> 4, tj = tid & 15;
    float acc[4][4];
#pragma unroll
    for (int i = 0; i < 4; ++i)
#pragma unroll
        for (int j = 0; j < 4; ++j) acc[i][j] = 0.f;

#pragma unroll
    for (int k = 0; k < 64; k += 8) {
        uint4 a8[4], w8[4];
#pragma unroll
        for (int i = 0; i < 4; ++i)
            a8[i] = *reinterpret_cast<const uint4*>(&As16[ti + 16 * i][k]);
#pragma unroll
        for (int j = 0; j < 4; ++j)
            w8[j] = *reinterpret_cast<const uint4*>(&Ws16[tj + 16 * j][k]);
#pragma unroll
        for (int i = 0; i < 4; ++i)
#pragma unroll
            for (int j = 0; j < 4; ++j) {
                float c0 = acc[i][j];
                c0 = fdot2u(a8[i].x, w8[j].x, c0);
                c0 = fdot2u(a8[i].y, w8[j].y, c0);
                c0 = fdot2u(a8[i].z, w8[j].z, c0);
                c0 = fdot2u(a8[i].w, w8[j].w, c0);
                acc[i][j] = c0;
            }
    }

    // epilogue per slice
    if (slice == 0) {
#pragma unroll
        for (int i = 0; i < 4; ++i) {
            int r = r0 + ti + 16 * i;
            if (r < M)
#pragma unroll
                for (int j = 0; j < 4; ++j)
                    Pt[(size_t)r * 64 + tj + 16 * j] = acc[i][j];
        }
    } else if (slice == 1) {
#pragma unroll
        for (int i = 0; i < 4; ++i) {
            int r = r0 + ti + 16 * i;
            if (r < M)
#pragma unroll
                for (int j = 0; j < 4; ++j) {
                    int c = tj + 16 * j;
                    PQh2[((size_t)r * 64 + c) * 2 + 0] =
                        (unsigned short)f2bf(acc[i][j] + attn_b[c]);
                }
        }
    } else if (slice == 2) {
#pragma unroll
        for (int i = 0; i < 4; ++i) {
            int r = r0 + ti + 16 * i;
            if (r < M)
#pragma unroll
                for (int j = 0; j < 4; ++j) {
                    int c = tj + 16 * j;
                    PQh2[((size_t)r * 64 + c) * 2 + 1] =
                        (unsigned short)f2bf(acc[i][j] + aggr_b[c]);
                }
        }
    } else if (slice == 3) {
#pragma unroll
        for (int i = 0; i < 4; ++i) {
            int r = r0 + ti + 16 * i;
            if (r < Mr)
#pragma unroll
                for (int j = 0; j < 4; ++j)
                    PQr2[((size_t)r * 64 + tj + 16 * j) * 2 + 0] =
                        (unsigned short)f2bf(acc[i][j]);
        }
    } else {
#pragma unroll
        for (int i = 0; i < 4; ++i) {
            int r = r0 + ti + 16 * i;
            if (r < Mr)
#pragma unroll
                for (int j = 0; j < 4; ++j)
                    PQr2[((size_t)r * 64 + tj + 16 * j) * 2 + 1] =
                        (unsigned short)f2bf(acc[i][j]);
        }
    }
}

// ---------------------------------------------------------------------------
// Scan: per-block inclusive scan + block sums; then per-block base reduce.
// ---------------------------------------------------------------------------
__global__ __launch_bounds__(256) void scan_chunk(const int* __restrict__ deg, int n,
                                                  int* __restrict__ incl, int* __restrict__ bsums)
{
    __shared__ int s[256];
    int tid = threadIdx.x;
    int i = blockIdx.x * 256 + tid;
    int v = (i < n) ? deg[i] : 0;
    int acc = v;
    s[tid] = acc;
    __syncthreads();
#pragma unroll
    for (int off = 1; off < 256; off <<= 1) {
        int add = (tid >= off) ? s[tid - off] : 0;
        __syncthreads();
        acc += add;
        s[tid] = acc;
        __syncthreads();
    }
    if (i < n) incl[i] = acc;
    if (tid == 255) bsums[blockIdx.x] = acc;
}

__global__ __launch_bounds__(256) void scan_final2(const int* __restrict__ deg,
                                                   const int* __restrict__ incl,
                                                   const int* __restrict__ bsums, int n,
                                                   int* __restrict__ offs)
{
    __shared__ int s[256];
    const int tid = threadIdx.x;
    int partial = 0;
    for (int i = tid; i < (int)blockIdx.x; i += 256) partial += bsums[i];
    s[tid] = partial;
    __syncthreads();
#pragma unroll
    for (int off = 128; off > 0; off >>= 1) {
        if (tid < off) s[tid] += s[tid + off];
        __syncthreads();
    }
    const int base = s[0];
    int i = blockIdx.x * 256 + tid;
    if (i < n)
        offs[i] = incl[i] - deg[i] + base;
}

// Atomic-free placement: p = offs[tail] + rank (rank captured in histogram).
__global__ __launch_bounds__(256) void place_kernel(const int* __restrict__ head,
                                                    const int* __restrict__ tail,
                                                    const int* __restrict__ rel, int E,
                                                    const int* __restrict__ offs,
                                                    const int* __restrict__ rank,
                                                    unsigned int* __restrict__ shr)
{
    const int base = (blockIdx.x * 256 + threadIdx.x) * 4;
    if (base + 4 <= E) {
        int4 h  = *reinterpret_cast<const int4*>(head + base);
        int4 t  = *reinterpret_cast<const int4*>(tail + base);
        int4 r  = *reinterpret_cast<const int4*>(rel + base);
        int4 rk = *reinterpret_cast<const int4*>(rank + base);
        shr[offs[t.x] + rk.x] = ((unsigned)h.x << 8) | (unsigned)r.x;
        shr[offs[t.y] + rk.y] = ((unsigned)h.y << 8) | (unsigned)r.y;
        shr[offs[t.z] + rk.z] = ((unsigned)h.z << 8) | (unsigned)r.z;
        shr[offs[t.w] + rk.w] = ((unsigned)h.w << 8) | (unsigned)r.w;
    } else {
        for (int k = 0; k < 4; ++k) {
            int e = base + k;
            if (e < E)
                shr[offs[tail[e]] + rank[e]] =
                    ((unsigned)head[e] << 8) | (unsigned)rel[e];
        }
    }
}

// ---------------------------------------------------------------------------
// Main: one wave per node, lane = output dim. Predicated 8-edge pipeline with
// ping-pong prefetch; tail edges clamp to a valid address and contribute 0
// via a 0/1 mask. PQh/PQr bf16-packed, 256 B row stride. DPP head reduce.
// No-max softmax. (Frozen from R11.)
// ---------------------------------------------------------------------------
__global__ __launch_bounds__(256) void ingram_main(
    const float* __restrict__ Pt,
    const unsigned* __restrict__ PQh,    // {bf16 Ph+attn_b | bf16 Qh+aggr_b}
    const unsigned* __restrict__ PQr,    // {bf16 Pr | bf16 Qr}
    const int* __restrict__ deg, const int* __restrict__ off,
    const unsigned* __restrict__ shr,
    const float* __restrict__ attn_vec,
    float* __restrict__ out, int N)
{
    const int lane = threadIdx.x & 63;
    const int node = blockIdx.x * 4 + (threadIdx.x >> 6);
    if (node >= N) return;

    const float vec = attn_vec[lane];
    const float ptd = Pt[(size_t)node * 64 + lane];
    const char* HBc = (const char*)PQh;
    const char* RBc = (const char*)PQr;
    const unsigned loff4 = (unsigned)lane << 2;

    const int start = __builtin_amdgcn_readfirstlane(off[node]);
    const int dg    = __builtin_amdgcn_readfirstlane(deg[node]);

    float S = 0.f, O = 0.f, SP = 0.f, SQ = 0.f;

    const int ng = (dg + 7) >> 3;        // groups of 8 edges
    unsigned Ah[8], Ar8[8], Bh[8], Br8[8];

#define LOADG(gbase, H, R)                                                   \
    {                                                                        \
        _Pragma("unroll")                                                    \
        for (int k = 0; k < 8; ++k) {                                        \
            int idx = (gbase) + k;                                           \
            int e   = start + ((idx < dg) ? idx : (dg - 1));                 \
            unsigned p = shr[e];  /* uniform addr -> scalar load */          \
            H[k] = *(const unsigned*)(HBc + (p & 0xFFFFFF00u) + loff4);      \
            R[k] = *(const unsigned*)(RBc + ((p & 255u) << 8) + loff4);      \
        }                                                                    \
    }

#define COMPUTE(gbase, H, R)                                                 \
    {                                                                        \
        _Pragma("unroll")                                                    \
        for (int k = 0; k < 8; ++k) {                                        \
            const int idx = (gbase) + k;                                     \
            const float valid = (idx < dg) ? 1.f : 0.f;                      \
            unsigned hb = H[k], rb = R[k];                                   \
            float hx = __uint_as_float(hb << 16);                            \
            float hy = __uint_as_float(hb & 0xFFFF0000u);                    \
            float rx = __uint_as_float(rb << 16);                            \
            float ry = __uint_as_float(rb & 0xFFFF0000u);                    \
            SP = fmaf(rx, valid, SP);                                        \
            SQ = fmaf(ry, valid, SQ);                                        \
            float pre = ptd + hx + rx;                                       \
            float a   = fmaxf(pre, 0.2f * pre);                              \
            float t   = a * vec;                                             \
            t = dpp_add_xor1(t);                                             \
            t = dpp_add_xor2(t);                                             \
            t = dpp_add_mirr8(t);                                            \
            float av = __expf(t) * valid;                                    \
            S += av;                                                         \
            O = fmaf(av, hy + ry, O);                                        \
        }                                                                    \
    }

    if (ng > 0) LOADG(0, Ah, Ar8);
    for (int g = 0; g < ng; g += 2) {
        if (g + 1 < ng) LOADG((g + 1) * 8, Bh, Br8);
        COMPUTE(g * 8, Ah, Ar8);
        if (g + 1 < ng) {
            if (g + 2 < ng) LOADG((g + 2) * 8, Ah, Ar8);
            COMPUTE((g + 1) * 8, Bh, Br8);
        }
    }
#undef LOADG
#undef COMPUTE

    // self-loop: rel features = (sum of incoming Pr/Qr)/(deg+eps)
    {
        const float inv = 1.f / ((float)dg + EPS);
        unsigned hb = *(const unsigned*)(HBc + ((unsigned)node << 8) + loff4);
        float hx = __uint_as_float(hb << 16);
        float hy = __uint_as_float(hb & 0xFFFF0000u);
        float pre = ptd + hx + SP * inv;
        float a   = fmaxf(pre, 0.2f * pre);
        float t   = a * vec;
        t = dpp_add_xor1(t);
        t = dpp_add_xor2(t);
        t = dpp_add_mirr8(t);
        float av = __expf(t);
        S += av;
        O = fmaf(av, hy + SQ * inv, O);
    }

    out[(size_t)node * 64 + lane] = O / (S + EPS);
}

// ---------------------------------------------------------------------------
extern "C" void kernel_launch(void* const* d_in, const int* in_sizes, int n_in,
                              void* d_out, int out_size, void* d_ws, size_t ws_size,
                              hipStream_t stream)
{
    const float* emb_ent  = (const float*)d_in[0];
    const float* emb_rel  = (const float*)d_in[1];
    const float* attn_W   = (const float*)d_in[2];   // [64 x 192]
    const float* attn_b   = (const float*)d_in[3];
    const float* attn_vec = (const float*)d_in[4];   // 64
    const float* aggr_W   = (const float*)d_in[5];   // [64 x 128]
    const float* aggr_b   = (const float*)d_in[6];
    const int*   head     = (const int*)d_in[7];
    const int*   tail     = (const int*)d_in[8];
    const int*   rel      = (const int*)d_in[9];

    const int N = in_sizes[0] / 64;
    const int R = in_sizes[1] / 64;
    const int E = in_sizes[7];

    char* w = (char*)d_ws;
    float*    Pt  = (float*)w;        w += (size_t)N * 64 * sizeof(float);
    unsigned* PQh = (unsigned*)w;     w += (size_t)N * 64 * sizeof(unsigned);
    unsigned* PQr = (unsigned*)w;     w += (size_t)R * 64 * sizeof(unsigned);
    int* deg    = (int*)w;            w += (size_t)N * sizeof(int);
    int* incl   = (int*)w;            w += (size_t)N * sizeof(int);
    int* offs   = (int*)w;            w += (size_t)N * sizeof(int);
    int* bsums  = (int*)w;            w += 256 * sizeof(int);
    int* rank   = (int*)w;            w += (size_t)E * sizeof(int);
    unsigned int* shr = (unsigned int*)w;  w += (size_t)E * sizeof(unsigned int);

    hipMemsetAsync(deg, 0, (size_t)N * sizeof(int), stream);

    // fused: histogram (first, rank-capturing) + 5 GEMM slice ranges
    int gN = (N + 63) / 64;
    int gr = (R + 63) / 64;
    int gH = (E + 1023) / 1024;
    tables_hist<<<gH + 3 * gN + 2 * gr, 256, 0, stream>>>(
        emb_ent, N, emb_rel, R, attn_W, aggr_W, attn_b, aggr_b,
        Pt, (unsigned short*)PQh, (unsigned short*)PQr,
        tail, E, deg, rank, gN, gr, gH);

    int nb = (N + 255) / 256;
    scan_chunk<<<nb, 256, 0, stream>>>(deg, N, incl, bsums);
    scan_final2<<<nb, 256, 0, stream>>>(deg, incl, bsums, N, offs);
    place_kernel<<<(E + 1023) / 1024, 256, 0, stream>>>(head, tail, rel, E,
                                                        offs, rank, shr);

    // per-node aggregation
    ingram_main<<<(N + 3) / 4, 256, 0, stream>>>(Pt, PQh, PQr, deg, offs, shr,
                                                 attn_vec, (float*)d_out, N);
}